// Round 1
// baseline (921.224 us; speedup 1.0000x reference)
//
#include <hip/hip_runtime.h>
#include <hip/hip_bf16.h>

#define VOCAB 30522
#define HIDDEN 768
#define NHEADS 4
#define NHID 128
#define ROWS 2048
#define KDIM 512
#define LN_EPS 1e-12f
#define ALPHA_LR 0.01f
#define NEGV -9.0e15f
#define NTILE 239   // ceil(30522/128)

typedef __attribute__((ext_vector_type(8))) short short8;
typedef __attribute__((ext_vector_type(4))) float floatx4;
typedef __attribute__((ext_vector_type(4))) unsigned short ushort4v;

static __device__ __forceinline__ unsigned short f2bf(float f) {
  unsigned int u = __float_as_uint(f);
  unsigned int r = u + 0x7fffu + ((u >> 16) & 1u);
  return (unsigned short)(r >> 16);
}

// ---------------- kernel 0: out_W fp32 -> bf16 ----------------
__global__ __launch_bounds__(256) void k_convert(const float* __restrict__ src,
                                                 unsigned short* __restrict__ dst, int n4) {
  int i = blockIdx.x * blockDim.x + threadIdx.x;
  int stride = gridDim.x * blockDim.x;
  for (; i < n4; i += stride) {
    floatx4 v = reinterpret_cast<const floatx4*>(src)[i];
    ushort4v o;
    o.x = f2bf(v.x); o.y = f2bf(v.y); o.z = f2bf(v.z); o.w = f2bf(v.w);
    reinterpret_cast<ushort4v*>(dst)[i] = o;
  }
}

// ---------------- kernel 1: embeddings + LayerNorm ----------------
__global__ __launch_bounds__(256) void k_embed_ln(const int* __restrict__ tok, const int* __restrict__ typ,
    const float* __restrict__ tok_emb, const float* __restrict__ type_emb, const float* __restrict__ pos_emb,
    const float* __restrict__ ln_g, const float* __restrict__ ln_b, float* __restrict__ xout) {
  int row = blockIdx.x;
  int n = row & 255;
  int t = tok[row], ty = typ[row];
  const float* te = tok_emb + (long)t * HIDDEN;
  const float* ye = type_emb + (long)ty * HIDDEN;
  const float* pe = pos_emb + (long)n * HIDDEN;
  float v[3]; float s = 0.f, ss = 0.f;
  #pragma unroll
  for (int q = 0; q < 3; q++) {
    int d = threadIdx.x + q * 256;
    float x = te[d] + ye[d] + pe[d];
    v[q] = x; s += x; ss += x * x;
  }
  __shared__ float red[8];
  for (int off = 32; off; off >>= 1) { s += __shfl_down(s, off); ss += __shfl_down(ss, off); }
  int wid = threadIdx.x >> 6;
  if ((threadIdx.x & 63) == 0) { red[wid] = s; red[4 + wid] = ss; }
  __syncthreads();
  if (threadIdx.x == 0) {
    float a = red[0] + red[1] + red[2] + red[3];
    float b = red[4] + red[5] + red[6] + red[7];
    float mu = a * (1.0f / 768.0f);
    float var = b * (1.0f / 768.0f) - mu * mu;
    red[0] = mu; red[1] = rsqrtf(var + LN_EPS);
  }
  __syncthreads();
  float mu = red[0], rstd = red[1];
  #pragma unroll
  for (int q = 0; q < 3; q++) {
    int d = threadIdx.x + q * 256;
    xout[(long)row * HIDDEN + d] = (v[q] - mu) * rstd * ln_g[d] + ln_b[d];
  }
}

// ---------------- kernel 2: Wh = x @ W (fp32 tiled GEMM) ----------------
// x: (2048,768), W: (4,768,128) -> Wh stored as [h][row][f]
__global__ __launch_bounds__(256) void k_wh(const float* __restrict__ x, const float* __restrict__ W,
                                            float* __restrict__ Wh) {
  int bm = blockIdx.x & 31, bn = blockIdx.x >> 5;   // 32 x 8
  int m0 = bm * 64, n0 = bn * 64;
  __shared__ float As[16][65];
  __shared__ float Bs[16][64];
  int tx = threadIdx.x & 15, ty = threadIdx.x >> 4;
  float acc[4][4] = {};
  for (int k0 = 0; k0 < HIDDEN; k0 += 16) {
    #pragma unroll
    for (int q = 0; q < 4; q++) {
      int e = threadIdx.x + q * 256;
      int m = e >> 4, k = e & 15;
      As[k][m] = x[(long)(m0 + m) * HIDDEN + k0 + k];
    }
    #pragma unroll
    for (int q = 0; q < 4; q++) {
      int e = threadIdx.x + q * 256;
      int nn = e & 63, k = e >> 6;
      int c = n0 + nn;
      Bs[k][nn] = W[((long)(c >> 7) * HIDDEN + (k0 + k)) * NHID + (c & 127)];
    }
    __syncthreads();
    #pragma unroll
    for (int k = 0; k < 16; k++) {
      float av[4], bv[4];
      #pragma unroll
      for (int i = 0; i < 4; i++) av[i] = As[k][ty * 4 + i];
      #pragma unroll
      for (int j = 0; j < 4; j++) bv[j] = Bs[k][tx * 4 + j];
      #pragma unroll
      for (int i = 0; i < 4; i++)
        #pragma unroll
        for (int j = 0; j < 4; j++) acc[i][j] += av[i] * bv[j];
    }
    __syncthreads();
  }
  #pragma unroll
  for (int i = 0; i < 4; i++)
    #pragma unroll
    for (int j = 0; j < 4; j++) {
      int row = m0 + ty * 4 + i, c = n0 + tx * 4 + j;
      Wh[((long)(c >> 7) * ROWS + row) * NHID + (c & 127)] = acc[i][j];
    }
}

// ---------------- kernel 3: e1/e2 = Wh . a1/a2 ----------------
__global__ __launch_bounds__(256) void k_e12(const float* __restrict__ Wh, const float* __restrict__ a,
                                             float* __restrict__ e1, float* __restrict__ e2) {
  int h = blockIdx.x >> 3, b = blockIdx.x & 7;
  __shared__ float av[256];
  av[threadIdx.x] = a[h * 256 + threadIdx.x];
  __syncthreads();
  int row = b * 256 + threadIdx.x;
  const float* wr = Wh + ((long)h * ROWS + row) * NHID;
  float s1 = 0.f, s2 = 0.f;
  #pragma unroll 8
  for (int f = 0; f < 128; f++) { float w = wr[f]; s1 += w * av[f]; s2 += w * av[128 + f]; }
  e1[h * ROWS + row] = s1; e2[h * ROWS + row] = s2;
}

__device__ __forceinline__ unsigned char mk_flags(int t, int hwv, int tokv) {
  unsigned char fl = 0;
  if (hwv) {
    if (t == 1) fl |= 1;
    if (t == 3) fl |= 2;
    if (t == 0 || t == 2 || t == 5) fl |= 4;
    if (t == 6 || t == 4 || t == 0) fl |= 8;
  }
  if (tokv != 0) fl |= 16;
  return fl;
}

// ---------------- kernel 4a: column-wise softmax stats (max over i, sum over i) ----------------
__global__ __launch_bounds__(256) void k_colstats(const int* __restrict__ tok, const int* __restrict__ typ,
    const int* __restrict__ syn, const int* __restrict__ hw,
    const float* __restrict__ e1, const float* __restrict__ e2,
    float* __restrict__ colmax, float* __restrict__ colrs) {
  int h = blockIdx.x >> 3, b = blockIdx.x & 7;
  __shared__ float E1[256]; __shared__ int SY[256]; __shared__ unsigned char FL[256];
  int tid = threadIdx.x;
  int g = b * 256 + tid;
  FL[tid] = mk_flags(typ[g], hw[g], tok[g]);
  E1[tid] = e1[h * ROWS + g];
  SY[tid] = syn[g];
  __syncthreads();
  float e2j = e2[h * ROWS + g];
  int syj = SY[tid]; unsigned char flj = FL[tid];
  bool npj = flj & 16, d1j = flj & 4, d3j = flj & 8;
  float m = -INFINITY;
  for (int i = 0; i < 256; i++) {
    float e = E1[i] + e2j;
    e = e > 0.f ? e : ALPHA_LR * e;
    unsigned char fli = FL[i];
    bool vis = (SY[i] == syj) || ((fli & 1) && d1j) || ((fli & 2) && d3j);
    float v = (vis && npj) ? e : NEGV;
    m = fmaxf(m, v);
  }
  float s = 0.f;
  for (int i = 0; i < 256; i++) {
    float e = E1[i] + e2j;
    e = e > 0.f ? e : ALPHA_LR * e;
    unsigned char fli = FL[i];
    bool vis = (SY[i] == syj) || ((fli & 1) && d1j) || ((fli & 2) && d3j);
    float v = (vis && npj) ? e : NEGV;
    s += __expf(v - m);
  }
  int idx = (h * 8 + b) * 256 + tid;
  colmax[idx] = m;
  colrs[idx] = 1.0f / s;
}

// ---------------- kernel 4b: hp = elu(att @ Wh) -> cat (bf16) ----------------
__global__ __launch_bounds__(256) void k_att(const int* __restrict__ tok, const int* __restrict__ typ,
    const int* __restrict__ syn, const int* __restrict__ hw,
    const float* __restrict__ e1, const float* __restrict__ e2,
    const float* __restrict__ colmax, const float* __restrict__ colrs,
    const float* __restrict__ Wh, unsigned short* __restrict__ cat) {
  int chunk = blockIdx.x & 3; int hb = blockIdx.x >> 2;
  int h = hb >> 3, b = hb & 7;
  __shared__ float E2[256], CM[256], CR[256];
  __shared__ int SY[256]; __shared__ unsigned char FL[256];
  __shared__ float WJ[64][128];
  int tid = threadIdx.x;
  {
    int g = b * 256 + tid;
    FL[tid] = mk_flags(typ[g], hw[g], tok[g]);
    E2[tid] = e2[h * ROWS + g];
    CM[tid] = colmax[hb * 256 + tid];
    CR[tid] = colrs[hb * 256 + tid];
    SY[tid] = syn[g];
  }
  __syncthreads();
  int i = chunk * 64 + (tid >> 2);
  int gi = b * 256 + i;
  float e1i = e1[h * ROWS + gi];
  unsigned char fli = FL[i];
  bool s1i = fli & 1, s3i = fli & 2;
  int syni = SY[i];
  int f0 = tid & 3;
  float acc[32] = {};
  for (int j0 = 0; j0 < 256; j0 += 64) {
    #pragma unroll
    for (int q = 0; q < 32; q++) {
      int e = tid + q * 256;
      int j = e >> 7, f = e & 127;
      WJ[j][f] = Wh[((long)h * ROWS + b * 256 + j0 + j) * NHID + f];
    }
    __syncthreads();
    for (int j = 0; j < 64; j++) {
      int jj = j0 + j;
      unsigned char flj = FL[jj];
      bool vis = (syni == SY[jj]) || (s1i && (flj & 4)) || (s3i && (flj & 8));
      bool msk = vis && (flj & 16);
      float ev = e1i + E2[jj];
      ev = ev > 0.f ? ev : ALPHA_LR * ev;
      float v = msk ? ev : NEGV;
      float w = __expf(v - CM[jj]) * CR[jj];
      #pragma unroll
      for (int k = 0; k < 32; k++) acc[k] += w * WJ[j][f0 + 4 * k];
    }
    __syncthreads();
  }
  unsigned short* cr = cat + (long)gi * KDIM + h * NHID;
  #pragma unroll
  for (int k = 0; k < 32; k++) {
    float v = acc[k];
    v = v > 0.f ? v : expm1f(v);
    cr[f0 + 4 * k] = f2bf(v);
  }
}

// ---------------- kernel 5: big GEMM (bf16 MFMA) + elu + bias + partial lse ----------------
// C(2048 x 30522) = cat(2048x512) @ owb(30522x512)^T ; writes elu'd vals + per-(row, col-64-tile) max/sumexp
__global__ __launch_bounds__(256) void k_gemm(const unsigned short* __restrict__ A,
    const unsigned short* __restrict__ Bw, const float* __restrict__ bias,
    float* __restrict__ out, float* __restrict__ pm, float* __restrict__ ps) {
  int bid = blockIdx.x;
  int mt = bid & 15, nt = bid >> 4;
  int m0 = mt * 128, n0 = nt * 128;
  __shared__ __align__(16) unsigned short Al[128 * 72];
  __shared__ __align__(16) unsigned short Bl[128 * 72];
  int tid = threadIdx.x;
  int l = tid & 63, wid = tid >> 6;
  int wr = wid >> 1, wc = wid & 1;
  int lrow = l & 15, lgrp = l >> 4;
  floatx4 zero = {0.f, 0.f, 0.f, 0.f};
  floatx4 acc[4][4];
  #pragma unroll
  for (int i = 0; i < 4; i++)
    #pragma unroll
    for (int j = 0; j < 4; j++) acc[i][j] = zero;
  for (int kt = 0; kt < 8; kt++) {
    #pragma unroll
    for (int q = 0; q < 4; q++) {
      int chunk = tid + q * 256;
      int row = chunk >> 3, kp = chunk & 7;
      short8 av = *reinterpret_cast<const short8*>(A + (long)(m0 + row) * KDIM + kt * 64 + kp * 8);
      *reinterpret_cast<short8*>(&Al[row * 72 + kp * 8]) = av;
      int v = n0 + row;
      short8 bv = {0, 0, 0, 0, 0, 0, 0, 0};
      if (v < VOCAB) bv = *reinterpret_cast<const short8*>(Bw + (long)v * KDIM + kt * 64 + kp * 8);
      *reinterpret_cast<short8*>(&Bl[row * 72 + kp * 8]) = bv;
    }
    __syncthreads();
    #pragma unroll
    for (int kk = 0; kk < 2; kk++) {
      short8 af[4], bf[4];
      #pragma unroll
      for (int mi = 0; mi < 4; mi++)
        af[mi] = *reinterpret_cast<const short8*>(&Al[(wr * 64 + mi * 16 + lrow) * 72 + kk * 32 + lgrp * 8]);
      #pragma unroll
      for (int ni = 0; ni < 4; ni++)
        bf[ni] = *reinterpret_cast<const short8*>(&Bl[(wc * 64 + ni * 16 + lrow) * 72 + kk * 32 + lgrp * 8]);
      #pragma unroll
      for (int mi = 0; mi < 4; mi++)
        #pragma unroll
        for (int ni = 0; ni < 4; ni++)
          acc[mi][ni] = __builtin_amdgcn_mfma_f32_16x16x32_bf16(af[mi], bf[ni], acc[mi][ni], 0, 0, 0);
    }
    __syncthreads();
  }
  // epilogue: bias + elu + store + per-row (within this wave's 64 cols) max/sumexp
  int t2 = nt * 2 + wc;
  float bcol[4]; bool valid[4]; int cols[4];
  #pragma unroll
  for (int ni = 0; ni < 4; ni++) {
    int c = n0 + wc * 64 + ni * 16 + lrow;
    cols[ni] = c; valid[ni] = c < VOCAB;
    bcol[ni] = valid[ni] ? bias[c] : 0.f;
  }
  #pragma unroll
  for (int mi = 0; mi < 4; mi++) {
    #pragma unroll
    for (int reg = 0; reg < 4; reg++) {
      int row = m0 + wr * 64 + mi * 16 + lgrp * 4 + reg;
      float vv[4]; float mx = -INFINITY;
      #pragma unroll
      for (int ni = 0; ni < 4; ni++) {
        float v = acc[mi][ni][reg] + bcol[ni];
        v = v > 0.f ? v : expm1f(v);
        vv[ni] = v;
        if (valid[ni]) mx = fmaxf(mx, v);
      }
      #pragma unroll
      for (int off = 1; off < 16; off <<= 1) mx = fmaxf(mx, __shfl_xor(mx, off));
      float se = 0.f;
      #pragma unroll
      for (int ni = 0; ni < 4; ni++) {
        if (valid[ni]) {
          se += __expf(vv[ni] - mx);
          out[(long)row * VOCAB + cols[ni]] = vv[ni];
        }
      }
      #pragma unroll
      for (int off = 1; off < 16; off <<= 1) se += __shfl_xor(se, off);
      if (lrow == 0) { pm[(long)t2 * ROWS + row] = mx; ps[(long)t2 * ROWS + row] = se; }
    }
  }
}

// ---------------- kernel 6: reduce partial (max, sumexp) -> lse per row ----------------
__global__ __launch_bounds__(256) void k_lse(const float* __restrict__ pm, const float* __restrict__ ps,
                                             float* __restrict__ lse) {
  int row = blockIdx.x * 256 + threadIdx.x;
  float M = -INFINITY;
  for (int t = 0; t < 2 * NTILE; t++) M = fmaxf(M, pm[(long)t * ROWS + row]);
  float S = 0.f;
  for (int t = 0; t < 2 * NTILE; t++) {
    float m = pm[(long)t * ROWS + row];
    float s = ps[(long)t * ROWS + row];
    if (s > 0.f) S += s * __expf(m - M);
  }
  lse[row] = M + logf(S);
}

// ---------------- kernel 7: out -= lse[row] ----------------
__global__ __launch_bounds__(256) void k_sub(float* __restrict__ out, const float* __restrict__ lse, int n4) {
  int i = blockIdx.x * blockDim.x + threadIdx.x;
  int stride = gridDim.x * blockDim.x;
  for (; i < n4; i += stride) {
    floatx4 v = reinterpret_cast<floatx4*>(out)[i];
    unsigned base = (unsigned)i * 4u;
    #pragma unroll
    for (int e = 0; e < 4; e++) {
      unsigned row = (base + e) / (unsigned)VOCAB;
      v[e] -= lse[row];
    }
    reinterpret_cast<floatx4*>(out)[i] = v;
  }
}

extern "C" void kernel_launch(void* const* d_in, const int* in_sizes, int n_in,
                              void* d_out, int out_size, void* d_ws, size_t ws_size,
                              hipStream_t stream) {
  const int* tok = (const int*)d_in[0];
  const int* typ = (const int*)d_in[1];
  const int* syn = (const int*)d_in[2];
  const int* hw  = (const int*)d_in[3];
  const float* tok_emb  = (const float*)d_in[4];
  const float* type_emb = (const float*)d_in[5];
  const float* pos_emb  = (const float*)d_in[6];
  const float* ln_g = (const float*)d_in[7];
  const float* ln_b = (const float*)d_in[8];
  const float* W    = (const float*)d_in[9];
  const float* a    = (const float*)d_in[10];
  const float* out_W = (const float*)d_in[11];
  const float* out_b = (const float*)d_in[12];
  float* out = (float*)d_out;
  char* ws = (char*)d_ws;
  // ws layout (bytes)
  float* x   = (float*)(ws + 0);                 // 2048*768*4   = 6291456
  float* Wh  = (float*)(ws + 6291456);           // 4*2048*128*4 = 4194304
  float* e1  = (float*)(ws + 10485760);          // 32768
  float* e2  = (float*)(ws + 10518528);          // 32768
  float* cm  = (float*)(ws + 10551296);          // 32768
  float* cs  = (float*)(ws + 10584064);          // 32768
  unsigned short* cat = (unsigned short*)(ws + 10616832);  // 2048*512*2 = 2097152
  unsigned short* owb = (unsigned short*)(ws + 12713984);  // 30522*512*2 = 31254528
  float* pm  = (float*)(ws + 43968512);          // 478*2048*4 = 3915776
  float* ps  = (float*)(ws + 47884288);          // 3915776
  float* lse = (float*)(ws + 51800064);          // 8192

  k_convert<<<2048, 256, 0, stream>>>(out_W, owb, (VOCAB * KDIM) / 4);
  k_embed_ln<<<2048, 256, 0, stream>>>(tok, typ, tok_emb, type_emb, pos_emb, ln_g, ln_b, x);
  k_wh<<<256, 256, 0, stream>>>(x, W, Wh);
  k_e12<<<32, 256, 0, stream>>>(Wh, a, e1, e2);
  k_colstats<<<32, 256, 0, stream>>>(tok, typ, syn, hw, e1, e2, cm, cs);
  k_att<<<128, 256, 0, stream>>>(tok, typ, syn, hw, e1, e2, cm, cs, Wh, cat);
  k_gemm<<<16 * NTILE, 256, 0, stream>>>(cat, owb, out_b, out, pm, ps);
  k_lse<<<8, 256, 0, stream>>>(pm, ps, lse);
  k_sub<<<2048, 256, 0, stream>>>(out, lse, (ROWS * VOCAB) / 4);
}

// Round 2
// 602.785 us; speedup vs baseline: 1.5283x; 1.5283x over previous
//
#include <hip/hip_runtime.h>
#include <hip/hip_bf16.h>

#define VOCAB 30522
#define HIDDEN 768
#define NHEADS 4
#define NHID 128
#define ROWS 2048
#define KDIM 512
#define LN_EPS 1e-12f
#define ALPHA_LR 0.01f
#define NEGV -9.0e15f
#define NTILE 239   // ceil(30522/128)
#define NT2 480     // padded partial count (2*NTILE=478, pad to 480)

typedef __attribute__((ext_vector_type(8))) short short8;
typedef __attribute__((ext_vector_type(4))) float floatx4;
typedef __attribute__((ext_vector_type(4))) unsigned short ushort4v;

static __device__ __forceinline__ unsigned short f2bf(float f) {
  unsigned int u = __float_as_uint(f);
  unsigned int r = u + 0x7fffu + ((u >> 16) & 1u);
  return (unsigned short)(r >> 16);
}

// ---------------- kernel 0: out_W fp32 -> bf16 ----------------
__global__ __launch_bounds__(256) void k_convert(const float* __restrict__ src,
                                                 unsigned short* __restrict__ dst, int n4) {
  int i = blockIdx.x * blockDim.x + threadIdx.x;
  int stride = gridDim.x * blockDim.x;
  for (; i < n4; i += stride) {
    floatx4 v = reinterpret_cast<const floatx4*>(src)[i];
    ushort4v o;
    o.x = f2bf(v.x); o.y = f2bf(v.y); o.z = f2bf(v.z); o.w = f2bf(v.w);
    reinterpret_cast<ushort4v*>(dst)[i] = o;
  }
}

// ---------------- kernel 1: embeddings + LayerNorm ----------------
__global__ __launch_bounds__(256) void k_embed_ln(const int* __restrict__ tok, const int* __restrict__ typ,
    const float* __restrict__ tok_emb, const float* __restrict__ type_emb, const float* __restrict__ pos_emb,
    const float* __restrict__ ln_g, const float* __restrict__ ln_b, float* __restrict__ xout) {
  int row = blockIdx.x;
  int n = row & 255;
  int t = tok[row], ty = typ[row];
  const float* te = tok_emb + (long)t * HIDDEN;
  const float* ye = type_emb + (long)ty * HIDDEN;
  const float* pe = pos_emb + (long)n * HIDDEN;
  float v[3]; float s = 0.f, ss = 0.f;
  #pragma unroll
  for (int q = 0; q < 3; q++) {
    int d = threadIdx.x + q * 256;
    float x = te[d] + ye[d] + pe[d];
    v[q] = x; s += x; ss += x * x;
  }
  __shared__ float red[8];
  for (int off = 32; off; off >>= 1) { s += __shfl_down(s, off); ss += __shfl_down(ss, off); }
  int wid = threadIdx.x >> 6;
  if ((threadIdx.x & 63) == 0) { red[wid] = s; red[4 + wid] = ss; }
  __syncthreads();
  if (threadIdx.x == 0) {
    float a = red[0] + red[1] + red[2] + red[3];
    float b = red[4] + red[5] + red[6] + red[7];
    float mu = a * (1.0f / 768.0f);
    float var = b * (1.0f / 768.0f) - mu * mu;
    red[0] = mu; red[1] = rsqrtf(var + LN_EPS);
  }
  __syncthreads();
  float mu = red[0], rstd = red[1];
  #pragma unroll
  for (int q = 0; q < 3; q++) {
    int d = threadIdx.x + q * 256;
    xout[(long)row * HIDDEN + d] = (v[q] - mu) * rstd * ln_g[d] + ln_b[d];
  }
}

// ---------------- kernel 2: Wh = x @ W (fp32 tiled GEMM) ----------------
__global__ __launch_bounds__(256) void k_wh(const float* __restrict__ x, const float* __restrict__ W,
                                            float* __restrict__ Wh) {
  int bm = blockIdx.x & 31, bn = blockIdx.x >> 5;   // 32 x 8
  int m0 = bm * 64, n0 = bn * 64;
  __shared__ float As[16][65];
  __shared__ float Bs[16][64];
  int tx = threadIdx.x & 15, ty = threadIdx.x >> 4;
  float acc[4][4] = {};
  for (int k0 = 0; k0 < HIDDEN; k0 += 16) {
    #pragma unroll
    for (int q = 0; q < 4; q++) {
      int e = threadIdx.x + q * 256;
      int m = e >> 4, k = e & 15;
      As[k][m] = x[(long)(m0 + m) * HIDDEN + k0 + k];
    }
    #pragma unroll
    for (int q = 0; q < 4; q++) {
      int e = threadIdx.x + q * 256;
      int nn = e & 63, k = e >> 6;
      int c = n0 + nn;
      Bs[k][nn] = W[((long)(c >> 7) * HIDDEN + (k0 + k)) * NHID + (c & 127)];
    }
    __syncthreads();
    #pragma unroll
    for (int k = 0; k < 16; k++) {
      float av[4], bv[4];
      #pragma unroll
      for (int i = 0; i < 4; i++) av[i] = As[k][ty * 4 + i];
      #pragma unroll
      for (int j = 0; j < 4; j++) bv[j] = Bs[k][tx * 4 + j];
      #pragma unroll
      for (int i = 0; i < 4; i++)
        #pragma unroll
        for (int j = 0; j < 4; j++) acc[i][j] += av[i] * bv[j];
    }
    __syncthreads();
  }
  #pragma unroll
  for (int i = 0; i < 4; i++)
    #pragma unroll
    for (int j = 0; j < 4; j++) {
      int row = m0 + ty * 4 + i, c = n0 + tx * 4 + j;
      Wh[((long)(c >> 7) * ROWS + row) * NHID + (c & 127)] = acc[i][j];
    }
}

// ---------------- kernel 3: e1/e2 = Wh . a1/a2 ----------------
__global__ __launch_bounds__(256) void k_e12(const float* __restrict__ Wh, const float* __restrict__ a,
                                             float* __restrict__ e1, float* __restrict__ e2) {
  int h = blockIdx.x >> 3, b = blockIdx.x & 7;
  __shared__ float av[256];
  av[threadIdx.x] = a[h * 256 + threadIdx.x];
  __syncthreads();
  int row = b * 256 + threadIdx.x;
  const float* wr = Wh + ((long)h * ROWS + row) * NHID;
  float s1 = 0.f, s2 = 0.f;
  #pragma unroll 8
  for (int f = 0; f < 128; f++) { float w = wr[f]; s1 += w * av[f]; s2 += w * av[128 + f]; }
  e1[h * ROWS + row] = s1; e2[h * ROWS + row] = s2;
}

__device__ __forceinline__ unsigned char mk_flags(int t, int hwv, int tokv) {
  unsigned char fl = 0;
  if (hwv) {
    if (t == 1) fl |= 1;
    if (t == 3) fl |= 2;
    if (t == 0 || t == 2 || t == 5) fl |= 4;
    if (t == 6 || t == 4 || t == 0) fl |= 8;
  }
  if (tokv != 0) fl |= 16;
  return fl;
}

// ---------------- kernel 4a: column-wise softmax stats ----------------
__global__ __launch_bounds__(256) void k_colstats(const int* __restrict__ tok, const int* __restrict__ typ,
    const int* __restrict__ syn, const int* __restrict__ hw,
    const float* __restrict__ e1, const float* __restrict__ e2,
    float* __restrict__ colmax, float* __restrict__ colrs) {
  int h = blockIdx.x >> 3, b = blockIdx.x & 7;
  __shared__ float E1[256]; __shared__ int SY[256]; __shared__ unsigned char FL[256];
  int tid = threadIdx.x;
  int g = b * 256 + tid;
  FL[tid] = mk_flags(typ[g], hw[g], tok[g]);
  E1[tid] = e1[h * ROWS + g];
  SY[tid] = syn[g];
  __syncthreads();
  float e2j = e2[h * ROWS + g];
  int syj = SY[tid]; unsigned char flj = FL[tid];
  bool npj = flj & 16, d1j = flj & 4, d3j = flj & 8;
  float m = -INFINITY;
  for (int i = 0; i < 256; i++) {
    float e = E1[i] + e2j;
    e = e > 0.f ? e : ALPHA_LR * e;
    unsigned char fli = FL[i];
    bool vis = (SY[i] == syj) || ((fli & 1) && d1j) || ((fli & 2) && d3j);
    float v = (vis && npj) ? e : NEGV;
    m = fmaxf(m, v);
  }
  float s = 0.f;
  for (int i = 0; i < 256; i++) {
    float e = E1[i] + e2j;
    e = e > 0.f ? e : ALPHA_LR * e;
    unsigned char fli = FL[i];
    bool vis = (SY[i] == syj) || ((fli & 1) && d1j) || ((fli & 2) && d3j);
    float v = (vis && npj) ? e : NEGV;
    s += __expf(v - m);
  }
  int idx = (h * 8 + b) * 256 + tid;
  colmax[idx] = m;
  colrs[idx] = 1.0f / s;
}

// ---------------- kernel 4b: hp = elu(att @ Wh) -> cat (bf16) ----------------
__global__ __launch_bounds__(256) void k_att(const int* __restrict__ tok, const int* __restrict__ typ,
    const int* __restrict__ syn, const int* __restrict__ hw,
    const float* __restrict__ e1, const float* __restrict__ e2,
    const float* __restrict__ colmax, const float* __restrict__ colrs,
    const float* __restrict__ Wh, unsigned short* __restrict__ cat) {
  int chunk = blockIdx.x & 3; int hb = blockIdx.x >> 2;
  int h = hb >> 3, b = hb & 7;
  __shared__ float E2[256], CM[256], CR[256];
  __shared__ int SY[256]; __shared__ unsigned char FL[256];
  __shared__ float WJ[64][128];
  int tid = threadIdx.x;
  {
    int g = b * 256 + tid;
    FL[tid] = mk_flags(typ[g], hw[g], tok[g]);
    E2[tid] = e2[h * ROWS + g];
    CM[tid] = colmax[hb * 256 + tid];
    CR[tid] = colrs[hb * 256 + tid];
    SY[tid] = syn[g];
  }
  __syncthreads();
  int i = chunk * 64 + (tid >> 2);
  int gi = b * 256 + i;
  float e1i = e1[h * ROWS + gi];
  unsigned char fli = FL[i];
  bool s1i = fli & 1, s3i = fli & 2;
  int syni = SY[i];
  int f0 = tid & 3;
  float acc[32] = {};
  for (int j0 = 0; j0 < 256; j0 += 64) {
    #pragma unroll
    for (int q = 0; q < 32; q++) {
      int e = tid + q * 256;
      int j = e >> 7, f = e & 127;
      WJ[j][f] = Wh[((long)h * ROWS + b * 256 + j0 + j) * NHID + f];
    }
    __syncthreads();
    for (int j = 0; j < 64; j++) {
      int jj = j0 + j;
      unsigned char flj = FL[jj];
      bool vis = (syni == SY[jj]) || (s1i && (flj & 4)) || (s3i && (flj & 8));
      bool msk = vis && (flj & 16);
      float ev = e1i + E2[jj];
      ev = ev > 0.f ? ev : ALPHA_LR * ev;
      float v = msk ? ev : NEGV;
      float w = __expf(v - CM[jj]) * CR[jj];
      #pragma unroll
      for (int k = 0; k < 32; k++) acc[k] += w * WJ[j][f0 + 4 * k];
    }
    __syncthreads();
  }
  unsigned short* cr = cat + (long)gi * KDIM + h * NHID;
  #pragma unroll
  for (int k = 0; k < 32; k++) {
    float v = acc[k];
    v = v > 0.f ? v : expm1f(v);
    cr[f0 + 4 * k] = f2bf(v);
  }
}

// ---------------- kernel 5: big GEMM (bf16 MFMA) + elu + bias + partial lse ----------------
__global__ __launch_bounds__(256) void k_gemm(const unsigned short* __restrict__ A,
    const unsigned short* __restrict__ Bw, const float* __restrict__ bias,
    float* __restrict__ out, float* __restrict__ pm, float* __restrict__ ps) {
  int bid = blockIdx.x;
  int mt = bid & 15, nt = bid >> 4;
  int m0 = mt * 128, n0 = nt * 128;
  __shared__ __align__(16) unsigned short Al[128 * 72];
  __shared__ __align__(16) unsigned short Bl[128 * 72];
  int tid = threadIdx.x;
  int l = tid & 63, wid = tid >> 6;
  int wr = wid >> 1, wc = wid & 1;
  int lrow = l & 15, lgrp = l >> 4;
  floatx4 zero = {0.f, 0.f, 0.f, 0.f};
  floatx4 acc[4][4];
  #pragma unroll
  for (int i = 0; i < 4; i++)
    #pragma unroll
    for (int j = 0; j < 4; j++) acc[i][j] = zero;
  for (int kt = 0; kt < 8; kt++) {
    #pragma unroll
    for (int q = 0; q < 4; q++) {
      int chunk = tid + q * 256;
      int row = chunk >> 3, kp = chunk & 7;
      short8 av = *reinterpret_cast<const short8*>(A + (long)(m0 + row) * KDIM + kt * 64 + kp * 8);
      *reinterpret_cast<short8*>(&Al[row * 72 + kp * 8]) = av;
      int v = n0 + row;
      short8 bv = {0, 0, 0, 0, 0, 0, 0, 0};
      if (v < VOCAB) bv = *reinterpret_cast<const short8*>(Bw + (long)v * KDIM + kt * 64 + kp * 8);
      *reinterpret_cast<short8*>(&Bl[row * 72 + kp * 8]) = bv;
    }
    __syncthreads();
    #pragma unroll
    for (int kk = 0; kk < 2; kk++) {
      short8 af[4], bf[4];
      #pragma unroll
      for (int mi = 0; mi < 4; mi++)
        af[mi] = *reinterpret_cast<const short8*>(&Al[(wr * 64 + mi * 16 + lrow) * 72 + kk * 32 + lgrp * 8]);
      #pragma unroll
      for (int ni = 0; ni < 4; ni++)
        bf[ni] = *reinterpret_cast<const short8*>(&Bl[(wc * 64 + ni * 16 + lrow) * 72 + kk * 32 + lgrp * 8]);
      #pragma unroll
      for (int mi = 0; mi < 4; mi++)
        #pragma unroll
        for (int ni = 0; ni < 4; ni++)
          acc[mi][ni] = __builtin_amdgcn_mfma_f32_16x16x32_bf16(af[mi], bf[ni], acc[mi][ni], 0, 0, 0);
    }
    __syncthreads();
  }
  // epilogue: bias + elu + store + per-row (within this wave's 64 cols) max/sumexp
  int t2 = nt * 2 + wc;
  float bcol[4]; bool valid[4]; int cols[4];
  #pragma unroll
  for (int ni = 0; ni < 4; ni++) {
    int c = n0 + wc * 64 + ni * 16 + lrow;
    cols[ni] = c; valid[ni] = c < VOCAB;
    bcol[ni] = valid[ni] ? bias[c] : 0.f;
  }
  #pragma unroll
  for (int mi = 0; mi < 4; mi++) {
    #pragma unroll
    for (int reg = 0; reg < 4; reg++) {
      int row = m0 + wr * 64 + mi * 16 + lgrp * 4 + reg;
      float vv[4]; float mx = -INFINITY;
      #pragma unroll
      for (int ni = 0; ni < 4; ni++) {
        float v = acc[mi][ni][reg] + bcol[ni];
        v = v > 0.f ? v : expm1f(v);
        vv[ni] = v;
        if (valid[ni]) mx = fmaxf(mx, v);
      }
      #pragma unroll
      for (int off = 1; off < 16; off <<= 1) mx = fmaxf(mx, __shfl_xor(mx, off));
      float se = 0.f;
      #pragma unroll
      for (int ni = 0; ni < 4; ni++) {
        if (valid[ni]) {
          se += __expf(vv[ni] - mx);
          out[(long)row * VOCAB + cols[ni]] = vv[ni];
        }
      }
      #pragma unroll
      for (int off = 1; off < 16; off <<= 1) se += __shfl_xor(se, off);
      if (lrow == 0) { pm[(long)row * NT2 + t2] = mx; ps[(long)row * NT2 + t2] = se; }
    }
  }
}

// ---------------- kernel 6: reduce partial (max, sumexp) -> lse per row ----------------
// one block per row; 256 threads cover 478 partials (2 each), tree-reduce
__global__ __launch_bounds__(256) void k_lse(const float* __restrict__ pm, const float* __restrict__ ps,
                                             float* __restrict__ lse) {
  int row = blockIdx.x;
  int tid = threadIdx.x;
  const float* pmr = pm + (long)row * NT2;
  const float* psr = ps + (long)row * NT2;
  float m0 = (tid < 478) ? pmr[tid] : -INFINITY;
  float m1 = (tid + 256 < 478) ? pmr[tid + 256] : -INFINITY;
  float s0 = (tid < 478) ? psr[tid] : 0.f;
  float s1 = (tid + 256 < 478) ? psr[tid + 256] : 0.f;
  float m = fmaxf(m0, m1);
  #pragma unroll
  for (int off = 32; off; off >>= 1) m = fmaxf(m, __shfl_xor(m, off));
  __shared__ float red[8];
  int wid = tid >> 6;
  if ((tid & 63) == 0) red[wid] = m;
  __syncthreads();
  float M = fmaxf(fmaxf(red[0], red[1]), fmaxf(red[2], red[3]));
  float s = (s0 > 0.f ? s0 * __expf(m0 - M) : 0.f) + (s1 > 0.f ? s1 * __expf(m1 - M) : 0.f);
  #pragma unroll
  for (int off = 32; off; off >>= 1) s += __shfl_xor(s, off);
  if ((tid & 63) == 0) red[4 + wid] = s;
  __syncthreads();
  if (tid == 0) lse[row] = M + logf(red[4] + red[5] + red[6] + red[7]);
}

// ---------------- kernel 7: out -= lse[row] ----------------
__global__ __launch_bounds__(256) void k_sub(float* __restrict__ out, const float* __restrict__ lse, int n4) {
  int i = blockIdx.x * blockDim.x + threadIdx.x;
  int stride = gridDim.x * blockDim.x;
  for (; i < n4; i += stride) {
    floatx4 v = reinterpret_cast<floatx4*>(out)[i];
    unsigned base = (unsigned)i * 4u;
    #pragma unroll
    for (int e = 0; e < 4; e++) {
      unsigned row = (base + e) / (unsigned)VOCAB;
      v[e] -= lse[row];
    }
    reinterpret_cast<floatx4*>(out)[i] = v;
  }
}

extern "C" void kernel_launch(void* const* d_in, const int* in_sizes, int n_in,
                              void* d_out, int out_size, void* d_ws, size_t ws_size,
                              hipStream_t stream) {
  const int* tok = (const int*)d_in[0];
  const int* typ = (const int*)d_in[1];
  const int* syn = (const int*)d_in[2];
  const int* hw  = (const int*)d_in[3];
  const float* tok_emb  = (const float*)d_in[4];
  const float* type_emb = (const float*)d_in[5];
  const float* pos_emb  = (const float*)d_in[6];
  const float* ln_g = (const float*)d_in[7];
  const float* ln_b = (const float*)d_in[8];
  const float* W    = (const float*)d_in[9];
  const float* a    = (const float*)d_in[10];
  const float* out_W = (const float*)d_in[11];
  const float* out_b = (const float*)d_in[12];
  float* out = (float*)d_out;
  char* ws = (char*)d_ws;
  // ws layout (bytes)
  float* x   = (float*)(ws + 0);                 // 2048*768*4   = 6291456
  float* Wh  = (float*)(ws + 6291456);           // 4*2048*128*4 = 4194304
  float* e1  = (float*)(ws + 10485760);          // 32768
  float* e2  = (float*)(ws + 10518528);          // 32768
  float* cm  = (float*)(ws + 10551296);          // 32768
  float* cs  = (float*)(ws + 10584064);          // 32768
  unsigned short* cat = (unsigned short*)(ws + 10616832);  // 2048*512*2 = 2097152
  unsigned short* owb = (unsigned short*)(ws + 12713984);  // 30522*512*2 = 31254528
  float* pm  = (float*)(ws + 43968512);          // 2048*480*4 = 3932160
  float* ps  = (float*)(ws + 47900672);          // 3932160
  float* lse = (float*)(ws + 51832832);          // 8192

  k_convert<<<2048, 256, 0, stream>>>(out_W, owb, (VOCAB * KDIM) / 4);
  k_embed_ln<<<2048, 256, 0, stream>>>(tok, typ, tok_emb, type_emb, pos_emb, ln_g, ln_b, x);
  k_wh<<<256, 256, 0, stream>>>(x, W, Wh);
  k_e12<<<32, 256, 0, stream>>>(Wh, a, e1, e2);
  k_colstats<<<32, 256, 0, stream>>>(tok, typ, syn, hw, e1, e2, cm, cs);
  k_att<<<128, 256, 0, stream>>>(tok, typ, syn, hw, e1, e2, cm, cs, Wh, cat);
  k_gemm<<<16 * NTILE, 256, 0, stream>>>(cat, owb, out_b, out, pm, ps);
  k_lse<<<2048, 256, 0, stream>>>(pm, ps, lse);
  k_sub<<<2048, 256, 0, stream>>>(out, lse, (ROWS * VOCAB) / 4);
}

// Round 3
// 560.241 us; speedup vs baseline: 1.6443x; 1.0759x over previous
//
#include <hip/hip_runtime.h>
#include <hip/hip_bf16.h>

#define VOCAB 30522
#define VPAD 30592   // VOCAB padded to multiple of 128 (for branch-free B staging)
#define HIDDEN 768
#define NHEADS 4
#define NHID 128
#define ROWS 2048
#define KDIM 512
#define LN_EPS 1e-12f
#define ALPHA_LR 0.01f
#define NEGV -9.0e15f
#define NTILE 239   // ceil(30522/128)
#define NT2 480     // padded partial count (2*NTILE=478, pad to 480)

typedef __attribute__((ext_vector_type(8))) short short8;
typedef __attribute__((ext_vector_type(4))) float floatx4;
typedef __attribute__((ext_vector_type(2))) float floatx2;
typedef __attribute__((ext_vector_type(4))) unsigned short ushort4v;

static __device__ __forceinline__ unsigned short f2bf(float f) {
  unsigned int u = __float_as_uint(f);
  unsigned int r = u + 0x7fffu + ((u >> 16) & 1u);
  return (unsigned short)(r >> 16);
}

// async global->LDS, 16B per lane (dest must be wave-linear: base + lane*16)
static __device__ __forceinline__ void gload16(const unsigned short* g, unsigned short* l) {
  __builtin_amdgcn_global_load_lds(
      (const __attribute__((address_space(1))) void*)g,
      (__attribute__((address_space(3))) void*)l, 16, 0, 0);
}

// ---------------- kernel 0: out_W fp32 -> bf16 (+ zero pad rows) ----------------
__global__ __launch_bounds__(256) void k_convert(const float* __restrict__ src,
                                                 unsigned short* __restrict__ dst,
                                                 int n4src, int n4tot) {
  int i = blockIdx.x * blockDim.x + threadIdx.x;
  int stride = gridDim.x * blockDim.x;
  for (; i < n4tot; i += stride) {
    ushort4v o = {0, 0, 0, 0};
    if (i < n4src) {
      floatx4 v = reinterpret_cast<const floatx4*>(src)[i];
      o.x = f2bf(v.x); o.y = f2bf(v.y); o.z = f2bf(v.z); o.w = f2bf(v.w);
    }
    reinterpret_cast<ushort4v*>(dst)[i] = o;
  }
}

// ---------------- kernel 1: embeddings + LayerNorm ----------------
__global__ __launch_bounds__(256) void k_embed_ln(const int* __restrict__ tok, const int* __restrict__ typ,
    const float* __restrict__ tok_emb, const float* __restrict__ type_emb, const float* __restrict__ pos_emb,
    const float* __restrict__ ln_g, const float* __restrict__ ln_b, float* __restrict__ xout) {
  int row = blockIdx.x;
  int n = row & 255;
  int t = tok[row], ty = typ[row];
  const float* te = tok_emb + (long)t * HIDDEN;
  const float* ye = type_emb + (long)ty * HIDDEN;
  const float* pe = pos_emb + (long)n * HIDDEN;
  float v[3]; float s = 0.f, ss = 0.f;
  #pragma unroll
  for (int q = 0; q < 3; q++) {
    int d = threadIdx.x + q * 256;
    float x = te[d] + ye[d] + pe[d];
    v[q] = x; s += x; ss += x * x;
  }
  __shared__ float red[8];
  for (int off = 32; off; off >>= 1) { s += __shfl_down(s, off); ss += __shfl_down(ss, off); }
  int wid = threadIdx.x >> 6;
  if ((threadIdx.x & 63) == 0) { red[wid] = s; red[4 + wid] = ss; }
  __syncthreads();
  if (threadIdx.x == 0) {
    float a = red[0] + red[1] + red[2] + red[3];
    float b = red[4] + red[5] + red[6] + red[7];
    float mu = a * (1.0f / 768.0f);
    float var = b * (1.0f / 768.0f) - mu * mu;
    red[0] = mu; red[1] = rsqrtf(var + LN_EPS);
  }
  __syncthreads();
  float mu = red[0], rstd = red[1];
  #pragma unroll
  for (int q = 0; q < 3; q++) {
    int d = threadIdx.x + q * 256;
    xout[(long)row * HIDDEN + d] = (v[q] - mu) * rstd * ln_g[d] + ln_b[d];
  }
}

// ---------------- kernel 2: Wh = x @ W (fp32 tiled GEMM) ----------------
__global__ __launch_bounds__(256) void k_wh(const float* __restrict__ x, const float* __restrict__ W,
                                            float* __restrict__ Wh) {
  int bm = blockIdx.x & 31, bn = blockIdx.x >> 5;   // 32 x 8
  int m0 = bm * 64, n0 = bn * 64;
  __shared__ float As[16][65];
  __shared__ float Bs[16][64];
  int tx = threadIdx.x & 15, ty = threadIdx.x >> 4;
  float acc[4][4] = {};
  for (int k0 = 0; k0 < HIDDEN; k0 += 16) {
    #pragma unroll
    for (int q = 0; q < 4; q++) {
      int e = threadIdx.x + q * 256;
      int m = e >> 4, k = e & 15;
      As[k][m] = x[(long)(m0 + m) * HIDDEN + k0 + k];
    }
    #pragma unroll
    for (int q = 0; q < 4; q++) {
      int e = threadIdx.x + q * 256;
      int nn = e & 63, k = e >> 6;
      int c = n0 + nn;
      Bs[k][nn] = W[((long)(c >> 7) * HIDDEN + (k0 + k)) * NHID + (c & 127)];
    }
    __syncthreads();
    #pragma unroll
    for (int k = 0; k < 16; k++) {
      float av[4], bv[4];
      #pragma unroll
      for (int i = 0; i < 4; i++) av[i] = As[k][ty * 4 + i];
      #pragma unroll
      for (int j = 0; j < 4; j++) bv[j] = Bs[k][tx * 4 + j];
      #pragma unroll
      for (int i = 0; i < 4; i++)
        #pragma unroll
        for (int j = 0; j < 4; j++) acc[i][j] += av[i] * bv[j];
    }
    __syncthreads();
  }
  #pragma unroll
  for (int i = 0; i < 4; i++)
    #pragma unroll
    for (int j = 0; j < 4; j++) {
      int row = m0 + ty * 4 + i, c = n0 + tx * 4 + j;
      Wh[((long)(c >> 7) * ROWS + row) * NHID + (c & 127)] = acc[i][j];
    }
}

// ---------------- kernel 3: e1/e2 = Wh . a1/a2 ----------------
__global__ __launch_bounds__(256) void k_e12(const float* __restrict__ Wh, const float* __restrict__ a,
                                             float* __restrict__ e1, float* __restrict__ e2) {
  int h = blockIdx.x >> 3, b = blockIdx.x & 7;
  __shared__ float av[256];
  av[threadIdx.x] = a[h * 256 + threadIdx.x];
  __syncthreads();
  int row = b * 256 + threadIdx.x;
  const float* wr = Wh + ((long)h * ROWS + row) * NHID;
  float s1 = 0.f, s2 = 0.f;
  #pragma unroll 8
  for (int f = 0; f < 128; f++) { float w = wr[f]; s1 += w * av[f]; s2 += w * av[128 + f]; }
  e1[h * ROWS + row] = s1; e2[h * ROWS + row] = s2;
}

__device__ __forceinline__ unsigned char mk_flags(int t, int hwv, int tokv) {
  unsigned char fl = 0;
  if (hwv) {
    if (t == 1) fl |= 1;
    if (t == 3) fl |= 2;
    if (t == 0 || t == 2 || t == 5) fl |= 4;
    if (t == 6 || t == 4 || t == 0) fl |= 8;
  }
  if (tokv != 0) fl |= 16;
  return fl;
}

// ---------------- kernel 4a: column-wise softmax stats ----------------
__global__ __launch_bounds__(256) void k_colstats(const int* __restrict__ tok, const int* __restrict__ typ,
    const int* __restrict__ syn, const int* __restrict__ hw,
    const float* __restrict__ e1, const float* __restrict__ e2,
    float* __restrict__ colmax, float* __restrict__ colrs) {
  int h = blockIdx.x >> 3, b = blockIdx.x & 7;
  __shared__ float E1[256]; __shared__ int SY[256]; __shared__ unsigned char FL[256];
  int tid = threadIdx.x;
  int g = b * 256 + tid;
  FL[tid] = mk_flags(typ[g], hw[g], tok[g]);
  E1[tid] = e1[h * ROWS + g];
  SY[tid] = syn[g];
  __syncthreads();
  float e2j = e2[h * ROWS + g];
  int syj = SY[tid]; unsigned char flj = FL[tid];
  bool npj = flj & 16, d1j = flj & 4, d3j = flj & 8;
  float m = -INFINITY;
  for (int i = 0; i < 256; i++) {
    float e = E1[i] + e2j;
    e = e > 0.f ? e : ALPHA_LR * e;
    unsigned char fli = FL[i];
    bool vis = (SY[i] == syj) || ((fli & 1) && d1j) || ((fli & 2) && d3j);
    float v = (vis && npj) ? e : NEGV;
    m = fmaxf(m, v);
  }
  float s = 0.f;
  for (int i = 0; i < 256; i++) {
    float e = E1[i] + e2j;
    e = e > 0.f ? e : ALPHA_LR * e;
    unsigned char fli = FL[i];
    bool vis = (SY[i] == syj) || ((fli & 1) && d1j) || ((fli & 2) && d3j);
    float v = (vis && npj) ? e : NEGV;
    s += __expf(v - m);
  }
  int idx = (h * 8 + b) * 256 + tid;
  colmax[idx] = m;
  colrs[idx] = 1.0f / s;
}

// ---------------- kernel 4b: hp = elu(att @ Wh) -> cat (bf16) ----------------
__global__ __launch_bounds__(256) void k_att(const int* __restrict__ tok, const int* __restrict__ typ,
    const int* __restrict__ syn, const int* __restrict__ hw,
    const float* __restrict__ e1, const float* __restrict__ e2,
    const float* __restrict__ colmax, const float* __restrict__ colrs,
    const float* __restrict__ Wh, unsigned short* __restrict__ cat) {
  int chunk = blockIdx.x & 3; int hb = blockIdx.x >> 2;
  int h = hb >> 3, b = hb & 7;
  __shared__ float E2[256], CM[256], CR[256];
  __shared__ int SY[256]; __shared__ unsigned char FL[256];
  __shared__ float WJ[64][128];
  int tid = threadIdx.x;
  {
    int g = b * 256 + tid;
    FL[tid] = mk_flags(typ[g], hw[g], tok[g]);
    E2[tid] = e2[h * ROWS + g];
    CM[tid] = colmax[hb * 256 + tid];
    CR[tid] = colrs[hb * 256 + tid];
    SY[tid] = syn[g];
  }
  __syncthreads();
  int i = chunk * 64 + (tid >> 2);
  int gi = b * 256 + i;
  float e1i = e1[h * ROWS + gi];
  unsigned char fli = FL[i];
  bool s1i = fli & 1, s3i = fli & 2;
  int syni = SY[i];
  int f0 = tid & 3;
  float acc[32] = {};
  for (int j0 = 0; j0 < 256; j0 += 64) {
    #pragma unroll
    for (int q = 0; q < 32; q++) {
      int e = tid + q * 256;
      int j = e >> 7, f = e & 127;
      WJ[j][f] = Wh[((long)h * ROWS + b * 256 + j0 + j) * NHID + f];
    }
    __syncthreads();
    for (int j = 0; j < 64; j++) {
      int jj = j0 + j;
      unsigned char flj = FL[jj];
      bool vis = (syni == SY[jj]) || (s1i && (flj & 4)) || (s3i && (flj & 8));
      bool msk = vis && (flj & 16);
      float ev = e1i + E2[jj];
      ev = ev > 0.f ? ev : ALPHA_LR * ev;
      float v = msk ? ev : NEGV;
      float w = __expf(v - CM[jj]) * CR[jj];
      #pragma unroll
      for (int k = 0; k < 32; k++) acc[k] += w * WJ[j][f0 + 4 * k];
    }
    __syncthreads();
  }
  unsigned short* cr = cat + (long)gi * KDIM + h * NHID;
  #pragma unroll
  for (int k = 0; k < 32; k++) {
    float v = acc[k];
    v = v > 0.f ? v : expm1f(v);
    cr[f0 + 4 * k] = f2bf(v);
  }
}

// ---------------- kernel 5: big GEMM (bf16 MFMA, global_load_lds staging) ----------------
// C(2048 x 30522) = cat(2048x512) @ owb(VPAD x 512)^T ; elu+bias fused; partial lse per (row, 64-col tile)
__global__ __launch_bounds__(256) void k_gemm(const unsigned short* __restrict__ A,
    const unsigned short* __restrict__ Bw, const float* __restrict__ bias,
    float* __restrict__ out, float* __restrict__ pm, float* __restrict__ ps) {
  // bijective XCD swizzle: 3824 blocks, 3824 % 8 == 0
  int bid = blockIdx.x;
  bid = (bid & 7) * ((16 * NTILE) >> 3) + (bid >> 3);
  int mt = bid & 15, nt = bid >> 4;
  int m0 = mt * 128, n0 = nt * 128;
  __shared__ __align__(16) unsigned short Al[128 * 64];
  __shared__ __align__(16) unsigned short Bl[128 * 64];
  int tid = threadIdx.x;
  int l = tid & 63, wid = tid >> 6;
  int wr = wid >> 1, wc = wid & 1;
  int lrow = l & 15, lgrp = l >> 4;
  floatx4 zero = {0.f, 0.f, 0.f, 0.f};
  floatx4 acc[4][4];
  #pragma unroll
  for (int i = 0; i < 4; i++)
    #pragma unroll
    for (int j = 0; j < 4; j++) acc[i][j] = zero;
  const unsigned short* Ab = A + (long)m0 * KDIM;
  const unsigned short* Bb = Bw + (long)n0 * KDIM;
  for (int kt = 0; kt < 8; kt++) {
    // stage A,B tiles: 128 rows x 64 k, linear LDS (dest = base + lane*16)
    #pragma unroll
    for (int q = 0; q < 4; q++) {
      int chunk = q * 256 + tid;
      int row = chunk >> 3, kp = chunk & 7;
      gload16(Ab + (long)row * KDIM + kt * 64 + kp * 8, &Al[chunk * 8]);
      gload16(Bb + (long)row * KDIM + kt * 64 + kp * 8, &Bl[chunk * 8]);
    }
    __syncthreads();   // compiler drains vmcnt before barrier
    #pragma unroll
    for (int kk = 0; kk < 2; kk++) {
      short8 af[4], bf[4];
      #pragma unroll
      for (int mi = 0; mi < 4; mi++)
        af[mi] = *reinterpret_cast<const short8*>(&Al[(wr * 64 + mi * 16 + lrow) * 64 + kk * 32 + lgrp * 8]);
      #pragma unroll
      for (int ni = 0; ni < 4; ni++)
        bf[ni] = *reinterpret_cast<const short8*>(&Bl[(wc * 64 + ni * 16 + lrow) * 64 + kk * 32 + lgrp * 8]);
      #pragma unroll
      for (int mi = 0; mi < 4; mi++)
        #pragma unroll
        for (int ni = 0; ni < 4; ni++)
          acc[mi][ni] = __builtin_amdgcn_mfma_f32_16x16x32_bf16(af[mi], bf[ni], acc[mi][ni], 0, 0, 0);
    }
    __syncthreads();
  }
  // epilogue: bias + elu + store + per-row (within this wave's 64 cols) max/sumexp
  int t2 = nt * 2 + wc;
  float bcol[4]; bool valid[4]; int cols[4];
  #pragma unroll
  for (int ni = 0; ni < 4; ni++) {
    int c = n0 + wc * 64 + ni * 16 + lrow;
    cols[ni] = c; valid[ni] = c < VOCAB;
    bcol[ni] = valid[ni] ? bias[c] : 0.f;
  }
  #pragma unroll
  for (int mi = 0; mi < 4; mi++) {
    #pragma unroll
    for (int reg = 0; reg < 4; reg++) {
      int row = m0 + wr * 64 + mi * 16 + lgrp * 4 + reg;
      float vv[4]; float mx = -INFINITY;
      #pragma unroll
      for (int ni = 0; ni < 4; ni++) {
        float v = acc[mi][ni][reg] + bcol[ni];
        v = v > 0.f ? v : expm1f(v);
        vv[ni] = v;
        if (valid[ni]) mx = fmaxf(mx, v);
      }
      #pragma unroll
      for (int off = 1; off < 16; off <<= 1) mx = fmaxf(mx, __shfl_xor(mx, off));
      float se = 0.f;
      #pragma unroll
      for (int ni = 0; ni < 4; ni++) {
        if (valid[ni]) {
          se += __expf(vv[ni] - mx);
          out[(long)row * VOCAB + cols[ni]] = vv[ni];
        }
      }
      #pragma unroll
      for (int off = 1; off < 16; off <<= 1) se += __shfl_xor(se, off);
      if (lrow == 0) { pm[(long)row * NT2 + t2] = mx; ps[(long)row * NT2 + t2] = se; }
    }
  }
}

// ---------------- kernel 6: reduce partial (max, sumexp) -> lse per row ----------------
__global__ __launch_bounds__(256) void k_lse(const float* __restrict__ pm, const float* __restrict__ ps,
                                             float* __restrict__ lse) {
  int row = blockIdx.x;
  int tid = threadIdx.x;
  const float* pmr = pm + (long)row * NT2;
  const float* psr = ps + (long)row * NT2;
  float m0 = (tid < 478) ? pmr[tid] : -INFINITY;
  float m1 = (tid + 256 < 478) ? pmr[tid + 256] : -INFINITY;
  float s0 = (tid < 478) ? psr[tid] : 0.f;
  float s1 = (tid + 256 < 478) ? psr[tid + 256] : 0.f;
  float m = fmaxf(m0, m1);
  #pragma unroll
  for (int off = 32; off; off >>= 1) m = fmaxf(m, __shfl_xor(m, off));
  __shared__ float red[8];
  int wid = tid >> 6;
  if ((tid & 63) == 0) red[wid] = m;
  __syncthreads();
  float M = fmaxf(fmaxf(red[0], red[1]), fmaxf(red[2], red[3]));
  float s = (s0 > 0.f ? s0 * __expf(m0 - M) : 0.f) + (s1 > 0.f ? s1 * __expf(m1 - M) : 0.f);
  #pragma unroll
  for (int off = 32; off; off >>= 1) s += __shfl_xor(s, off);
  if ((tid & 63) == 0) red[4 + wid] = s;
  __syncthreads();
  if (tid == 0) lse[row] = M + logf(red[4] + red[5] + red[6] + red[7]);
}

// ---------------- kernel 7: out -= lse[row] (2D grid, no divisions) ----------------
__global__ __launch_bounds__(256) void k_sub(float* __restrict__ out, const float* __restrict__ lse) {
  int row = blockIdx.y;
  float L = lse[row];
  floatx2* o = reinterpret_cast<floatx2*>(out + (long)row * VOCAB);
  int base = blockIdx.x * 1024 + threadIdx.x;
  #pragma unroll
  for (int k = 0; k < 4; k++) {
    int c2 = base + k * 256;
    if (c2 < VOCAB / 2) {
      floatx2 v = o[c2];
      v.x -= L; v.y -= L;
      o[c2] = v;
    }
  }
}

extern "C" void kernel_launch(void* const* d_in, const int* in_sizes, int n_in,
                              void* d_out, int out_size, void* d_ws, size_t ws_size,
                              hipStream_t stream) {
  const int* tok = (const int*)d_in[0];
  const int* typ = (const int*)d_in[1];
  const int* syn = (const int*)d_in[2];
  const int* hw  = (const int*)d_in[3];
  const float* tok_emb  = (const float*)d_in[4];
  const float* type_emb = (const float*)d_in[5];
  const float* pos_emb  = (const float*)d_in[6];
  const float* ln_g = (const float*)d_in[7];
  const float* ln_b = (const float*)d_in[8];
  const float* W    = (const float*)d_in[9];
  const float* a    = (const float*)d_in[10];
  const float* out_W = (const float*)d_in[11];
  const float* out_b = (const float*)d_in[12];
  float* out = (float*)d_out;
  char* ws = (char*)d_ws;
  // ws layout (bytes)
  float* x   = (float*)(ws + 0);                 // 2048*768*4   = 6291456
  float* Wh  = (float*)(ws + 6291456);           // 4*2048*128*4 = 4194304
  float* e1  = (float*)(ws + 10485760);          // 32768
  float* e2  = (float*)(ws + 10518528);          // 32768
  float* cm  = (float*)(ws + 10551296);          // 32768
  float* cs  = (float*)(ws + 10584064);          // 32768
  unsigned short* cat = (unsigned short*)(ws + 10616832);  // 2048*512*2 = 2097152
  unsigned short* owb = (unsigned short*)(ws + 12713984);  // VPAD*512*2 = 31326208
  float* pm  = (float*)(ws + 44040192);          // 2048*480*4 = 3932160
  float* ps  = (float*)(ws + 47972352);          // 3932160
  float* lse = (float*)(ws + 51904512);          // 8192

  k_convert<<<2048, 256, 0, stream>>>(out_W, owb, (VOCAB * KDIM) / 4, (VPAD * KDIM) / 4);
  k_embed_ln<<<2048, 256, 0, stream>>>(tok, typ, tok_emb, type_emb, pos_emb, ln_g, ln_b, x);
  k_wh<<<256, 256, 0, stream>>>(x, W, Wh);
  k_e12<<<32, 256, 0, stream>>>(Wh, a, e1, e2);
  k_colstats<<<32, 256, 0, stream>>>(tok, typ, syn, hw, e1, e2, cm, cs);
  k_att<<<128, 256, 0, stream>>>(tok, typ, syn, hw, e1, e2, cm, cs, Wh, cat);
  k_gemm<<<16 * NTILE, 256, 0, stream>>>(cat, owb, out_b, out, pm, ps);
  k_lse<<<2048, 256, 0, stream>>>(pm, ps, lse);
  k_sub<<<dim3(15, 2048), 256, 0, stream>>>(out, lse);
}